// Round 1
// baseline (1553.449 us; speedup 1.0000x reference)
//
#include <hip/hip_runtime.h>

#define N_NODES 100000
#define N_EDGES 1600000
#define NFEAT 128
#define NHID 64

// ---------------- GEMM: support = x @ W ----------------
// grid 3125 x 256. Each wave handles 8 nodes, lane = hid (64 hid).
// x reads are wave-uniform -> scalar loads; W reads coalesced.
__global__ __launch_bounds__(256) void gcn_gemm(const float* __restrict__ x,
                                                const float* __restrict__ W,
                                                float* __restrict__ support) {
  const int lane = threadIdx.x & 63;
  const int wave = __builtin_amdgcn_readfirstlane(threadIdx.x >> 6);
  const int node0 = blockIdx.x * 32 + wave * 8;
  const float* __restrict__ xr = x + (size_t)node0 * NFEAT;
  float acc[8];
#pragma unroll
  for (int n = 0; n < 8; ++n) acc[n] = 0.f;
#pragma unroll 4
  for (int k = 0; k < NFEAT; ++k) {
    const float wv = W[k * NHID + lane];
#pragma unroll
    for (int n = 0; n < 8; ++n)
      acc[n] = __builtin_fmaf(xr[(size_t)n * NFEAT + k], wv, acc[n]);
  }
#pragma unroll
  for (int n = 0; n < 8; ++n)
    support[(size_t)(node0 + n) * NHID + lane] = acc[n];
}

// ---------------- Edge scatter: out += val * support[col] ----------------
// 16 lanes per edge, float4 per lane. 1.6M*16/256 = 100000 blocks exactly.
__global__ __launch_bounds__(256) void gcn_scatter(const int* __restrict__ erow,
                                                   const int* __restrict__ ecol,
                                                   const float* __restrict__ eval_,
                                                   const float* __restrict__ support,
                                                   float* __restrict__ out) {
  const unsigned gid = blockIdx.x * 256u + threadIdx.x;
  const unsigned e = gid >> 4;
  const unsigned q = gid & 15u;
  const int r = erow[e];
  const int c = ecol[e];
  const float v = eval_[e];
  const float4 s = ((const float4*)support)[(size_t)c * 16 + q];
  float* o = out + (size_t)r * 64 + (size_t)q * 4;
  unsafeAtomicAdd(o + 0, v * s.x);
  unsafeAtomicAdd(o + 1, v * s.y);
  unsafeAtomicAdd(o + 2, v * s.z);
  unsafeAtomicAdd(o + 3, v * s.w);
}

// ---------------- Threefry-2x32, JAX partitionable 32-bit draw ----------------
// key = (0, 42)  [jax.random.key(42)]; counter = (hi=0, lo=i); draw = out0 ^ out1.
// keep (p=0.5)  <=>  uniform = ((bits>>9)|0x3F800000)-1.0 < 0.5  <=>  bit31(bits)==0.
__device__ __forceinline__ unsigned rotl32(unsigned v, int r) {
  return (v << r) | (v >> (32 - r));
}

__device__ __forceinline__ unsigned threefry_draw(unsigned i) {
  const unsigned ks0 = 0u;
  const unsigned ks1 = 42u;
  const unsigned ks2 = 0x1BD11BDAu ^ 42u;  // ks0 ^ ks1 ^ C
  unsigned x0 = 0u + ks0;   // hi counter + ks0
  unsigned x1 = i + ks1;    // lo counter + ks1
#define TF_ROUND(r) { x0 += x1; x1 = rotl32(x1, (r)); x1 ^= x0; }
  TF_ROUND(13) TF_ROUND(15) TF_ROUND(26) TF_ROUND(6)
  x0 += ks1; x1 += ks2 + 1u;
  TF_ROUND(17) TF_ROUND(29) TF_ROUND(16) TF_ROUND(24)
  x0 += ks2; x1 += ks0 + 2u;
  TF_ROUND(13) TF_ROUND(15) TF_ROUND(26) TF_ROUND(6)
  x0 += ks0; x1 += ks1 + 3u;
  TF_ROUND(17) TF_ROUND(29) TF_ROUND(16) TF_ROUND(24)
  x0 += ks1; x1 += ks2 + 4u;
  TF_ROUND(13) TF_ROUND(15) TF_ROUND(26) TF_ROUND(6)
  x0 += ks2; x1 += ks0 + 5u;
#undef TF_ROUND
  return x0 ^ x1;
}

// ---------------- Epilogue: out = dropout(relu(out + b)) in place ----------------
// 6.4M elems / 4 per thread = 1.6M threads = 6250 blocks exactly.
__global__ __launch_bounds__(256) void gcn_epilogue(float* __restrict__ out,
                                                    const float* __restrict__ b) {
  const unsigned gid = blockIdx.x * 256u + threadIdx.x;
  const unsigned i0 = gid * 4u;
  float4 v = ((float4*)out)[gid];
  const float4 bb = ((const float4*)b)[(i0 & 63u) >> 2];
  float h[4];
  h[0] = fmaxf(v.x + bb.x, 0.f);
  h[1] = fmaxf(v.y + bb.y, 0.f);
  h[2] = fmaxf(v.z + bb.z, 0.f);
  h[3] = fmaxf(v.w + bb.w, 0.f);
  float o[4];
#pragma unroll
  for (int j = 0; j < 4; ++j) {
    const bool keep = (threefry_draw(i0 + (unsigned)j) >> 31) == 0u;
    o[j] = keep ? h[j] * 2.0f : 0.0f;
  }
  ((float4*)out)[gid] = make_float4(o[0], o[1], o[2], o[3]);
}

extern "C" void kernel_launch(void* const* d_in, const int* in_sizes, int n_in,
                              void* d_out, int out_size, void* d_ws, size_t ws_size,
                              hipStream_t stream) {
  const float* x     = (const float*)d_in[0];
  const int*   erow  = (const int*)d_in[1];
  const int*   ecol  = (const int*)d_in[2];
  const float* eval_ = (const float*)d_in[3];
  const float* W     = (const float*)d_in[4];
  const float* b     = (const float*)d_in[5];
  float* out = (float*)d_out;
  float* support = (float*)d_ws;  // 100000*64*4 = 25.6 MB scratch

  hipMemsetAsync(d_out, 0, (size_t)N_NODES * NHID * sizeof(float), stream);
  hipLaunchKernelGGL(gcn_gemm, dim3(N_NODES / 32), dim3(256), 0, stream,
                     x, W, support);
  hipLaunchKernelGGL(gcn_scatter, dim3((N_EDGES * 16) / 256), dim3(256), 0, stream,
                     erow, ecol, eval_, support, out);
  hipLaunchKernelGGL(gcn_epilogue, dim3((N_NODES * NHID / 4) / 256), dim3(256), 0, stream,
                     out, b);
}

// Round 2
// 461.325 us; speedup vs baseline: 3.3674x; 3.3674x over previous
//
#include <hip/hip_runtime.h>

#define N_NODES 100000
#define N_EDGES 1600000
#define NFEAT 128
#define NHID 64
#define N_CHUNKS ((N_NODES + 255) / 256)   // 391

// ---------------- GEMM: support = x @ W ----------------
__global__ __launch_bounds__(256) void gcn_gemm(const float* __restrict__ x,
                                                const float* __restrict__ W,
                                                float* __restrict__ support) {
  const int lane = threadIdx.x & 63;
  const int wave = __builtin_amdgcn_readfirstlane(threadIdx.x >> 6);
  const int node0 = blockIdx.x * 32 + wave * 8;
  const float* __restrict__ xr = x + (size_t)node0 * NFEAT;
  float acc[8];
#pragma unroll
  for (int n = 0; n < 8; ++n) acc[n] = 0.f;
#pragma unroll 4
  for (int k = 0; k < NFEAT; ++k) {
    const float wv = W[k * NHID + lane];
#pragma unroll
    for (int n = 0; n < 8; ++n)
      acc[n] = __builtin_fmaf(xr[(size_t)n * NFEAT + k], wv, acc[n]);
  }
#pragma unroll
  for (int n = 0; n < 8; ++n)
    support[(size_t)(node0 + n) * NHID + lane] = acc[n];
}

// ---------------- CSR build ----------------
__global__ __launch_bounds__(256) void gcn_hist(const int* __restrict__ erow,
                                                int* __restrict__ deg) {
  const unsigned e = blockIdx.x * 256u + threadIdx.x;
  atomicAdd(&deg[erow[e]], 1);
}

__global__ __launch_bounds__(256) void gcn_chunk_sum(const int* __restrict__ deg,
                                                     int* __restrict__ partial) {
  __shared__ int sm[256];
  const int t = threadIdx.x;
  const int i = blockIdx.x * 256 + t;
  sm[t] = (i < N_NODES) ? deg[i] : 0;
  __syncthreads();
  for (int s = 128; s > 0; s >>= 1) {
    if (t < s) sm[t] += sm[t + s];
    __syncthreads();
  }
  if (t == 0) partial[blockIdx.x] = sm[0];
}

__global__ __launch_bounds__(512) void gcn_scan_partials(int* __restrict__ partial,
                                                         int* __restrict__ row_start) {
  __shared__ int sm[512];
  const int t = threadIdx.x;
  const int v = (t < N_CHUNKS) ? partial[t] : 0;
  sm[t] = v;
  __syncthreads();
  for (int off = 1; off < 512; off <<= 1) {
    int xv = (t >= off) ? sm[t - off] : 0;
    __syncthreads();
    sm[t] += xv;
    __syncthreads();
  }
  if (t < N_CHUNKS) partial[t] = sm[t] - v;  // exclusive
  if (t == 0) row_start[N_NODES] = N_EDGES;
}

__global__ __launch_bounds__(256) void gcn_chunk_scan(const int* __restrict__ deg,
                                                      const int* __restrict__ partial,
                                                      int* __restrict__ row_start,
                                                      int* __restrict__ cursor) {
  __shared__ int sm[256];
  const int t = threadIdx.x;
  const int i = blockIdx.x * 256 + t;
  const int v = (i < N_NODES) ? deg[i] : 0;
  sm[t] = v;
  __syncthreads();
  for (int off = 1; off < 256; off <<= 1) {
    int xv = (t >= off) ? sm[t - off] : 0;
    __syncthreads();
    sm[t] += xv;
    __syncthreads();
  }
  if (i < N_NODES) {
    const int start = partial[blockIdx.x] + sm[t] - v;  // exclusive
    row_start[i] = start;
    cursor[i] = start;
  }
}

__global__ __launch_bounds__(256) void gcn_fill(const int* __restrict__ erow,
                                                const int* __restrict__ ecol,
                                                const float* __restrict__ eval_,
                                                int* __restrict__ cursor,
                                                int2* __restrict__ csr) {
  const unsigned e = blockIdx.x * 256u + threadIdx.x;
  const int r = erow[e];
  const int pos = atomicAdd(&cursor[r], 1);
  csr[pos] = make_int2(ecol[e], __float_as_int(eval_[e]));
}

// ---------------- Threefry-2x32 (JAX partitionable), key (0,42) ----------------
__device__ __forceinline__ unsigned rotl32(unsigned v, int r) {
  return (v << r) | (v >> (32 - r));
}

__device__ __forceinline__ unsigned threefry_draw(unsigned i) {
  const unsigned ks0 = 0u;
  const unsigned ks1 = 42u;
  const unsigned ks2 = 0x1BD11BDAu ^ 42u;
  unsigned x0 = 0u + ks0;
  unsigned x1 = i + ks1;
#define TF_ROUND(r) { x0 += x1; x1 = rotl32(x1, (r)); x1 ^= x0; }
  TF_ROUND(13) TF_ROUND(15) TF_ROUND(26) TF_ROUND(6)
  x0 += ks1; x1 += ks2 + 1u;
  TF_ROUND(17) TF_ROUND(29) TF_ROUND(16) TF_ROUND(24)
  x0 += ks2; x1 += ks0 + 2u;
  TF_ROUND(13) TF_ROUND(15) TF_ROUND(26) TF_ROUND(6)
  x0 += ks0; x1 += ks1 + 3u;
  TF_ROUND(17) TF_ROUND(29) TF_ROUND(16) TF_ROUND(24)
  x0 += ks1; x1 += ks2 + 4u;
  TF_ROUND(13) TF_ROUND(15) TF_ROUND(26) TF_ROUND(6)
  x0 += ks2; x1 += ks0 + 5u;
#undef TF_ROUND
  return x0 ^ x1;
}

// ---------------- Aggregate (gather) + fused epilogue ----------------
// One wave per node, lane = hid. grid 25000 x 256 = 100000 waves.
__global__ __launch_bounds__(256) void gcn_aggregate(const int* __restrict__ row_start,
                                                     const int2* __restrict__ csr,
                                                     const float* __restrict__ support,
                                                     const float* __restrict__ b,
                                                     float* __restrict__ out) {
  const int node = (int)((blockIdx.x * 256u + threadIdx.x) >> 6);
  const int lane = threadIdx.x & 63;
  const int s = row_start[node];
  const int e = row_start[node + 1];
  float acc = 0.f;
  int i = s;
  for (; i + 2 <= e; i += 2) {
    const int2 p0 = csr[i];
    const int2 p1 = csr[i + 1];
    const float s0 = support[(size_t)p0.x * NHID + lane];
    const float s1 = support[(size_t)p1.x * NHID + lane];
    acc = __builtin_fmaf(__int_as_float(p0.y), s0, acc);
    acc = __builtin_fmaf(__int_as_float(p1.y), s1, acc);
  }
  if (i < e) {
    const int2 p = csr[i];
    acc = __builtin_fmaf(__int_as_float(p.y), support[(size_t)p.x * NHID + lane], acc);
  }
  const float h = fmaxf(acc + b[lane], 0.f);
  const unsigned idx = (unsigned)node * 64u + (unsigned)lane;
  const bool keep = (threefry_draw(idx) >> 31) == 0u;
  out[idx] = keep ? h * 2.0f : 0.0f;
}

extern "C" void kernel_launch(void* const* d_in, const int* in_sizes, int n_in,
                              void* d_out, int out_size, void* d_ws, size_t ws_size,
                              hipStream_t stream) {
  const float* x     = (const float*)d_in[0];
  const int*   erow  = (const int*)d_in[1];
  const int*   ecol  = (const int*)d_in[2];
  const float* eval_ = (const float*)d_in[3];
  const float* W     = (const float*)d_in[4];
  const float* b     = (const float*)d_in[5];
  float* out = (float*)d_out;

  // Workspace layout (bytes):
  char* ws = (char*)d_ws;
  float* support  = (float*)(ws);                        // 25,600,000
  int*   deg      = (int*)(ws + 25600000);               //    400,000
  int*   cursor   = (int*)(ws + 26000000);               //    400,000
  int*   row_start= (int*)(ws + 26400000);               //    400,004 (+pad)
  int2*  csr      = (int2*)(ws + 26800016);              // 12,800,000
  int*   partial  = (int*)(ws + 39600016);               //      1,564
  // total ~39.7 MB

  hipMemsetAsync(deg, 0, N_NODES * sizeof(int), stream);
  hipLaunchKernelGGL(gcn_gemm, dim3(N_NODES / 32), dim3(256), 0, stream, x, W, support);
  hipLaunchKernelGGL(gcn_hist, dim3(N_EDGES / 256), dim3(256), 0, stream, erow, deg);
  hipLaunchKernelGGL(gcn_chunk_sum, dim3(N_CHUNKS), dim3(256), 0, stream, deg, partial);
  hipLaunchKernelGGL(gcn_scan_partials, dim3(1), dim3(512), 0, stream, partial, row_start);
  hipLaunchKernelGGL(gcn_chunk_scan, dim3(N_CHUNKS), dim3(256), 0, stream, deg, partial,
                     row_start, cursor);
  hipLaunchKernelGGL(gcn_fill, dim3(N_EDGES / 256), dim3(256), 0, stream,
                     erow, ecol, eval_, cursor, csr);
  hipLaunchKernelGGL(gcn_aggregate, dim3(N_NODES / 4), dim3(256), 0, stream,
                     row_start, csr, support, b, out);
}